// Round 7
// baseline (1127.529 us; speedup 1.0000x reference)
//
#include <hip/hip_runtime.h>

// Problem constants (from reference setup_inputs)
constexpr int kB = 256;
constexpr int kT = 2048;
constexpr int kI = 32;
constexpr int kH = 64;
constexpr int kO = 16;
constexpr int kPadL = 2;
constexpr int kPadR = 3;
constexpr int kTp = kT + kPadL + kPadR;  // 2053
constexpr int kCT = 32;                  // timesteps per producer chunk
constexpr int kNC = kT / kCT;            // 64 chunks

constexpr float kS = 1.4426950408889634f;  // log2(e), folded into weights

// Dynamic-LDS byte layout:
//   [0,128)      rbufA (64 x f16)     [128,256)  rbufB
//   [256, +16K)  xinA double buffer   [16640, +16K) xinB
//   [33024, 33536) aggbuf (2 x 64 f32)
constexpr unsigned kRbufA = 0;
constexpr unsigned kRbufB = 128;
constexpr unsigned kXinA  = 256;
constexpr unsigned kXinBytes = kCT * kH * 4;          // 8192 per buffer
constexpr unsigned kXinB  = kXinA + 2 * kXinBytes;    // 16640
constexpr unsigned kAgg   = kXinB + 2 * kXinBytes;    // 33024
constexpr unsigned kSmemBytes = kAgg + 2 * kH * 4;    // 33536

typedef float    v2f __attribute__((ext_vector_type(2)));
typedef _Float16 v2h __attribute__((ext_vector_type(2)));
typedef unsigned v4u __attribute__((ext_vector_type(4)));

extern __shared__ char smem[];

__device__ __forceinline__ void pk_fma(v2f& d, v2f a, v2f b) {
  asm("v_pk_fma_f32 %0, %1, %2, %0" : "+v"(d) : "v"(a), "v"(b));
}

__device__ __forceinline__ v2h as_h2(unsigned u) {
  return __builtin_bit_cast(v2h, u);
}

__device__ __forceinline__ float dot2(v2h a, v2h b, float c) {
#if __has_builtin(__builtin_amdgcn_fdot2)
  return __builtin_amdgcn_fdot2(a, b, c, false);
#else
  return fmaf((float)a.x, (float)b.x, fmaf((float)a.y, (float)b.y, c));
#endif
}

__device__ __forceinline__ float exp2_fast(float x) {
#if __has_builtin(__builtin_amdgcn_exp2f)
  return __builtin_amdgcn_exp2f(x);
#else
  return exp2f(x);
#endif
}

// Issue-only DS blocks (no waits): write this chain's r, issue 8 broadcast
// reads (+ optional xin read). Waits are separate so the OTHER chain's
// compute overlaps this chain's LDS latency. DS completes in-order per wave.
#define ISSUE10(q0, q1, q2, q3, q4, q5, q6, q7, xn, raddr, rv, rbase, xaddr) \
  asm volatile(                                                              \
      "ds_write_b16 %9, %10\n\t"                                             \
      "ds_read_b128 %0, %11 offset:0\n\t"                                    \
      "ds_read_b128 %1, %11 offset:16\n\t"                                   \
      "ds_read_b128 %2, %11 offset:32\n\t"                                   \
      "ds_read_b128 %3, %11 offset:48\n\t"                                   \
      "ds_read_b128 %4, %11 offset:64\n\t"                                   \
      "ds_read_b128 %5, %11 offset:80\n\t"                                   \
      "ds_read_b128 %6, %11 offset:96\n\t"                                   \
      "ds_read_b128 %7, %11 offset:112\n\t"                                  \
      "ds_read_b32 %8, %12"                                                  \
      : "=v"(q0), "=v"(q1), "=v"(q2), "=v"(q3),                              \
        "=v"(q4), "=v"(q5), "=v"(q6), "=v"(q7), "=v"(xn)                     \
      : "v"(raddr), "v"(rv), "v"(rbase), "v"(xaddr))

#define ISSUE9(q0, q1, q2, q3, q4, q5, q6, q7, raddr, rv, rbase)             \
  asm volatile(                                                              \
      "ds_write_b16 %8, %9\n\t"                                              \
      "ds_read_b128 %0, %10 offset:0\n\t"                                    \
      "ds_read_b128 %1, %10 offset:16\n\t"                                   \
      "ds_read_b128 %2, %10 offset:32\n\t"                                   \
      "ds_read_b128 %3, %10 offset:48\n\t"                                   \
      "ds_read_b128 %4, %10 offset:64\n\t"                                   \
      "ds_read_b128 %5, %10 offset:80\n\t"                                   \
      "ds_read_b128 %6, %10 offset:96\n\t"                                   \
      "ds_read_b128 %7, %10 offset:112"                                      \
      : "=v"(q0), "=v"(q1), "=v"(q2), "=v"(q3),                              \
        "=v"(q4), "=v"(q5), "=v"(q6), "=v"(q7)                               \
      : "v"(raddr), "v"(rv), "v"(rbase))

// Wait until at most N DS ops remain outstanding; ties the quads (and xin)
// so dependent dots are ordered after the wait.
#define WAIT9(N, q0, q1, q2, q3, q4, q5, q6, q7, xn)                         \
  asm volatile("s_waitcnt lgkmcnt(" N ")"                                    \
               : "+v"(q0), "+v"(q1), "+v"(q2), "+v"(q3),                     \
                 "+v"(q4), "+v"(q5), "+v"(q6), "+v"(q7), "+v"(xn))

#define WAIT8(N, q0, q1, q2, q3, q4, q5, q6, q7)                             \
  asm volatile("s_waitcnt lgkmcnt(" N ")"                                    \
               : "+v"(q0), "+v"(q1), "+v"(q2), "+v"(q3),                     \
                 "+v"(q4), "+v"(q5), "+v"(q6), "+v"(q7))

__global__ __launch_bounds__(128) void rnn_fused(
    const float* __restrict__ x,
    const float* __restrict__ W_ih,
    const float* __restrict__ W_hh,
    const float* __restrict__ b_ih,
    const float* __restrict__ b_hh,
    const float* __restrict__ W_fc,
    const float* __restrict__ b_fc,
    float* __restrict__ out)
{
  const int b0 = blockIdx.x * 2;       // this block's two batch elements
  const int b1 = b0 + 1;
  const int lane = threadIdx.x & 63;   // hidden unit index
  const int wave = threadIdx.x >> 6;

  // bias' = 2*kS*(b_ih + b_hh + rowsum(W_hh row lane))
  float rowsum = 0.0f;
#pragma unroll
  for (int j = 0; j < kH; j += 4) {
    float4 v = *(const float4*)(W_hh + lane * kH + j);
    rowsum += (v.x + v.y) + (v.z + v.w);
  }
  const float bias2 = 2.0f * kS * (b_ih[lane] + b_hh[lane] + rowsum);

  if (wave == 1) {
    // ================= producer: xin for BOTH batches =================
    v2f wi2[kI / 2];  // 2*kS*W_ih[lane][i]
#pragma unroll
    for (int i = 0; i < kI; i += 4) {
      float4 v = *(const float4*)(W_ih + lane * kI + i);
      wi2[i / 2 + 0] = v2f{2.0f * kS * v.x, 2.0f * kS * v.y};
      wi2[i / 2 + 1] = v2f{2.0f * kS * v.z, 2.0f * kS * v.w};
    }
    const float* xbA = x + (size_t)b0 * kT * kI;
    const float* xbB = x + (size_t)b1 * kT * kI;

    auto fill = [&](int c, int buf) {
      const float* srcA = xbA + (size_t)c * kCT * kI;
      const float* srcB = xbB + (size_t)c * kCT * kI;
      float* dstA = (float*)(smem + kXinA + buf * kXinBytes);
      float* dstB = (float*)(smem + kXinB + buf * kXinBytes);
#pragma unroll 2
      for (int t = 0; t < kCT; ++t) {
        const float4* rowA = (const float4*)(srcA + t * kI);  // broadcast
        const float4* rowB = (const float4*)(srcB + t * kI);
        v2f aA0 = v2f{0.f, 0.f}, aA1 = v2f{0.f, 0.f};
        v2f aB0 = v2f{0.f, 0.f}, aB1 = v2f{0.f, 0.f};
#pragma unroll
        for (int i2 = 0; i2 < 8; ++i2) {
          float4 vA = rowA[i2];
          float4 vB = rowB[i2];
          pk_fma(aA0, wi2[2 * i2 + 0], v2f{vA.x, vA.y});
          pk_fma(aA1, wi2[2 * i2 + 1], v2f{vA.z, vA.w});
          pk_fma(aB0, wi2[2 * i2 + 0], v2f{vB.x, vB.y});
          pk_fma(aB1, wi2[2 * i2 + 1], v2f{vB.z, vB.w});
        }
        dstA[t * kH + lane] = bias2 + ((aA0.x + aA0.y) + (aA1.x + aA1.y));
        dstB[t * kH + lane] = bias2 + ((aB0.x + aB0.y) + (aB1.x + aB1.y));
      }
    };

    fill(0, 0);
    __syncthreads();  // buffer 0 ready
#pragma unroll 1
    for (int c = 0; c < kNC; ++c) {
      if (c + 1 < kNC) fill(c + 1, (c + 1) & 1);
      __syncthreads();  // end of chunk c
    }
    return;
  }

  // ================= consumer (wave 0): two interleaved chains ==========
  v2h wh[kH / 2];  // -4*kS*W_hh[lane][j] as fp16 pairs
#pragma unroll
  for (int j = 0; j < kH; j += 2) {
    float w0 = W_hh[lane * kH + j + 0];
    float w1 = W_hh[lane * kH + j + 1];
    wh[j / 2] = v2h{(_Float16)(-4.0f * kS * w0), (_Float16)(-4.0f * kS * w1)};
  }

  const unsigned raddrA = kRbufA + (unsigned)lane * 2u;
  const unsigned raddrB = kRbufB + (unsigned)lane * 2u;
  const unsigned rbaseA = kRbufA;
  const unsigned rbaseB = kRbufB;

  float rsumA = 0.0f, rsumB = 0.0f;
  unsigned rvA = (unsigned)__builtin_bit_cast(unsigned short, (_Float16)0.5f);
  unsigned rvB = rvA;

  // dots + tail for one chain: z' = xin + wh·r ; r = 1/(1+2^{z'})
  auto compute = [&](const v4u& A, const v4u& Bq, const v4u& C, const v4u& D,
                     const v4u& E, const v4u& F, const v4u& G, const v4u& H,
                     float xin, float& rsum, unsigned& rv) {
    float za = xin, zb = 0.0f, zc = 0.0f, zd = 0.0f;
    za = dot2(as_h2(A.x), wh[0], za);
    zb = dot2(as_h2(A.y), wh[1], zb);
    zc = dot2(as_h2(A.z), wh[2], zc);
    zd = dot2(as_h2(A.w), wh[3], zd);
    za = dot2(as_h2(Bq.x), wh[4], za);
    zb = dot2(as_h2(Bq.y), wh[5], zb);
    zc = dot2(as_h2(Bq.z), wh[6], zc);
    zd = dot2(as_h2(Bq.w), wh[7], zd);
    za = dot2(as_h2(C.x), wh[8], za);
    zb = dot2(as_h2(C.y), wh[9], zb);
    zc = dot2(as_h2(C.z), wh[10], zc);
    zd = dot2(as_h2(C.w), wh[11], zd);
    za = dot2(as_h2(D.x), wh[12], za);
    zb = dot2(as_h2(D.y), wh[13], zb);
    zc = dot2(as_h2(D.z), wh[14], zc);
    zd = dot2(as_h2(D.w), wh[15], zd);
    za = dot2(as_h2(E.x), wh[16], za);
    zb = dot2(as_h2(E.y), wh[17], zb);
    zc = dot2(as_h2(E.z), wh[18], zc);
    zd = dot2(as_h2(E.w), wh[19], zd);
    za = dot2(as_h2(F.x), wh[20], za);
    zb = dot2(as_h2(F.y), wh[21], zb);
    zc = dot2(as_h2(F.z), wh[22], zc);
    zd = dot2(as_h2(F.w), wh[23], zd);
    za = dot2(as_h2(G.x), wh[24], za);
    zb = dot2(as_h2(G.y), wh[25], zb);
    zc = dot2(as_h2(G.z), wh[26], zc);
    zd = dot2(as_h2(G.w), wh[27], zd);
    za = dot2(as_h2(H.x), wh[28], za);
    zb = dot2(as_h2(H.y), wh[29], zb);
    zc = dot2(as_h2(H.z), wh[30], zc);
    zd = dot2(as_h2(H.w), wh[31], zd);
    float z2 = (za + zb) + (zc + zd);   // = 2*z*log2e
    float t = exp2_fast(z2);            // e^{2z}; inf -> r = 0 (graceful)
    float r = __builtin_amdgcn_rcpf(1.0f + t);
    rsum += r;
    rv = (unsigned)__builtin_bit_cast(unsigned short, (_Float16)r);
  };

  v4u qA0, qA1, qA2, qA3, qA4, qA5, qA6, qA7;
  v4u qB0, qB1, qB2, qB3, qB4, qB5, qB6, qB7;
  float xnA, xnB;

  // ---- left padding: 2 steps per chain, pipelined (buf0 fills meanwhile) --
  ISSUE9(qA0, qA1, qA2, qA3, qA4, qA5, qA6, qA7, raddrA, rvA, rbaseA);
  ISSUE9(qB0, qB1, qB2, qB3, qB4, qB5, qB6, qB7, raddrB, rvB, rbaseB);
  WAIT8("9", qA0, qA1, qA2, qA3, qA4, qA5, qA6, qA7);
  compute(qA0, qA1, qA2, qA3, qA4, qA5, qA6, qA7, bias2, rsumA, rvA);
  ISSUE9(qA0, qA1, qA2, qA3, qA4, qA5, qA6, qA7, raddrA, rvA, rbaseA);
  WAIT8("9", qB0, qB1, qB2, qB3, qB4, qB5, qB6, qB7);
  compute(qB0, qB1, qB2, qB3, qB4, qB5, qB6, qB7, bias2, rsumB, rvB);
  ISSUE9(qB0, qB1, qB2, qB3, qB4, qB5, qB6, qB7, raddrB, rvB, rbaseB);
  WAIT8("9", qA0, qA1, qA2, qA3, qA4, qA5, qA6, qA7);
  compute(qA0, qA1, qA2, qA3, qA4, qA5, qA6, qA7, bias2, rsumA, rvA);
  WAIT8("0", qB0, qB1, qB2, qB3, qB4, qB5, qB6, qB7);
  compute(qB0, qB1, qB2, qB3, qB4, qB5, qB6, qB7, bias2, rsumB, rvB);
  __syncthreads();  // buffer 0 ready; no DS ops outstanding

#pragma unroll 1
  for (int c = 0; c < kNC; ++c) {
    const unsigned xbA = kXinA + (unsigned)(c & 1) * kXinBytes +
                         (unsigned)lane * 4u;
    const unsigned xbB = kXinB + (unsigned)(c & 1) * kXinBytes +
                         (unsigned)lane * 4u;
    ISSUE10(qA0, qA1, qA2, qA3, qA4, qA5, qA6, qA7, xnA,
            raddrA, rvA, rbaseA, xbA);
    ISSUE10(qB0, qB1, qB2, qB3, qB4, qB5, qB6, qB7, xnB,
            raddrB, rvB, rbaseB, xbB);
#pragma unroll 2
    for (int t = 0; t < kCT - 1; ++t) {
      WAIT9("10", qA0, qA1, qA2, qA3, qA4, qA5, qA6, qA7, xnA);
      compute(qA0, qA1, qA2, qA3, qA4, qA5, qA6, qA7, xnA, rsumA, rvA);
      ISSUE10(qA0, qA1, qA2, qA3, qA4, qA5, qA6, qA7, xnA,
              raddrA, rvA, rbaseA, xbA + (unsigned)(t + 1) * (kH * 4u));
      WAIT9("10", qB0, qB1, qB2, qB3, qB4, qB5, qB6, qB7, xnB);
      compute(qB0, qB1, qB2, qB3, qB4, qB5, qB6, qB7, xnB, rsumB, rvB);
      ISSUE10(qB0, qB1, qB2, qB3, qB4, qB5, qB6, qB7, xnB,
              raddrB, rvB, rbaseB, xbB + (unsigned)(t + 1) * (kH * 4u));
    }
    // last step of the chunk: no issue past the barrier
    WAIT9("10", qA0, qA1, qA2, qA3, qA4, qA5, qA6, qA7, xnA);
    compute(qA0, qA1, qA2, qA3, qA4, qA5, qA6, qA7, xnA, rsumA, rvA);
    WAIT9("0", qB0, qB1, qB2, qB3, qB4, qB5, qB6, qB7, xnB);
    compute(qB0, qB1, qB2, qB3, qB4, qB5, qB6, qB7, xnB, rsumB, rvB);
    __syncthreads();  // done with this buffer; nothing outstanding
  }

  // ---- right padding: 3 steps per chain, pipelined ----
  ISSUE9(qA0, qA1, qA2, qA3, qA4, qA5, qA6, qA7, raddrA, rvA, rbaseA);
  ISSUE9(qB0, qB1, qB2, qB3, qB4, qB5, qB6, qB7, raddrB, rvB, rbaseB);
  WAIT8("9", qA0, qA1, qA2, qA3, qA4, qA5, qA6, qA7);
  compute(qA0, qA1, qA2, qA3, qA4, qA5, qA6, qA7, bias2, rsumA, rvA);
  ISSUE9(qA0, qA1, qA2, qA3, qA4, qA5, qA6, qA7, raddrA, rvA, rbaseA);
  WAIT8("9", qB0, qB1, qB2, qB3, qB4, qB5, qB6, qB7);
  compute(qB0, qB1, qB2, qB3, qB4, qB5, qB6, qB7, bias2, rsumB, rvB);
  ISSUE9(qB0, qB1, qB2, qB3, qB4, qB5, qB6, qB7, raddrB, rvB, rbaseB);
  WAIT8("9", qA0, qA1, qA2, qA3, qA4, qA5, qA6, qA7);
  compute(qA0, qA1, qA2, qA3, qA4, qA5, qA6, qA7, bias2, rsumA, rvA);
  ISSUE9(qA0, qA1, qA2, qA3, qA4, qA5, qA6, qA7, raddrA, rvA, rbaseA);
  WAIT8("9", qB0, qB1, qB2, qB3, qB4, qB5, qB6, qB7);
  compute(qB0, qB1, qB2, qB3, qB4, qB5, qB6, qB7, bias2, rsumB, rvB);
  ISSUE9(qB0, qB1, qB2, qB3, qB4, qB5, qB6, qB7, raddrB, rvB, rbaseB);
  WAIT8("9", qA0, qA1, qA2, qA3, qA4, qA5, qA6, qA7);
  compute(qA0, qA1, qA2, qA3, qA4, qA5, qA6, qA7, bias2, rsumA, rvA);
  WAIT8("0", qB0, qB1, qB2, qB3, qB4, qB5, qB6, qB7);
  compute(qB0, qB1, qB2, qB3, qB4, qB5, qB6, qB7, bias2, rsumB, rvB);

  // ---- epilogue: mean over Tp, FC (16x64) + ReLU for both batches ----
  float* agg = (float*)(smem + kAgg);
  agg[lane]      = 1.0f - 2.0f * rsumA * (1.0f / (float)kTp);
  agg[kH + lane] = 1.0f - 2.0f * rsumB * (1.0f / (float)kTp);
  // single wave: compiler inserts the proper lgkm waits for its own DS ops
  if (lane < kO) {
    float accA = b_fc[lane];
    float accB = accA;
    const float* wf = W_fc + lane * kH;
#pragma unroll
    for (int j = 0; j < kH; ++j) {
      accA = fmaf(wf[j], agg[j], accA);
      accB = fmaf(wf[j], agg[kH + j], accB);
    }
    out[b0 * kO + lane] = fmaxf(accA, 0.0f);
    out[b1 * kO + lane] = fmaxf(accB, 0.0f);
  }
}

extern "C" void kernel_launch(void* const* d_in, const int* in_sizes, int n_in,
                              void* d_out, int out_size, void* d_ws, size_t ws_size,
                              hipStream_t stream) {
  const float* x    = (const float*)d_in[0];
  const float* W_ih = (const float*)d_in[1];
  const float* W_hh = (const float*)d_in[2];
  const float* b_ih = (const float*)d_in[3];
  const float* b_hh = (const float*)d_in[4];
  const float* W_fc = (const float*)d_in[5];
  const float* b_fc = (const float*)d_in[6];
  float* out = (float*)d_out;

  rnn_fused<<<dim3(kB / 2), dim3(128), kSmemBytes, stream>>>(
      x, W_ih, W_hh, b_ih, b_hh, W_fc, b_fc, out);
}

// Round 8
// 578.077 us; speedup vs baseline: 1.9505x; 1.9505x over previous
//
#include <hip/hip_runtime.h>

// Problem constants (from reference setup_inputs)
constexpr int kB = 256;
constexpr int kT = 2048;
constexpr int kI = 32;
constexpr int kH = 64;
constexpr int kO = 16;
constexpr int kPadL = 2;
constexpr int kPadR = 3;
constexpr int kTp = kT + kPadL + kPadR;  // 2053
constexpr int kCT = 64;                  // timesteps per producer chunk
constexpr int kNC = kT / kCT;            // 32 chunks

constexpr float kS = 1.4426950408889634f;  // log2(e), folded into weights

typedef float    v2f __attribute__((ext_vector_type(2)));
typedef _Float16 v2h __attribute__((ext_vector_type(2)));

// Packed fp32 FMA (same rate as scalar; halves instruction count for producer)
__device__ __forceinline__ void pk_fma(v2f& d, v2f a, v2f b) {
  asm("v_pk_fma_f32 %0, %1, %2, %0" : "+v"(d) : "v"(a), "v"(b));
}

__device__ __forceinline__ v2h as_h2(unsigned u) {
  return __builtin_bit_cast(v2h, u);
}

// f16 dot-2 with f32 accumulate (V_DOT2_F32_F16)
__device__ __forceinline__ float dot2(v2h a, v2h b, float c) {
#if __has_builtin(__builtin_amdgcn_fdot2)
  return __builtin_amdgcn_fdot2(a, b, c, false);
#else
  return fmaf((float)a.x, (float)b.x, fmaf((float)a.y, (float)b.y, c));
#endif
}

__device__ __forceinline__ float exp2_fast(float x) {
#if __has_builtin(__builtin_amdgcn_exp2f)
  return __builtin_amdgcn_exp2f(x);
#else
  return exp2f(x);
#endif
}

// Block = 2 waves per batch element. Wave 0 = serial recurrence (lane =
// hidden unit), wave 1 = input-projection producer, one chunk ahead,
// double-buffered in LDS. Chain communicates r_t = 1/(1+2^{z'_t})
// (h = 1-2r) via fp16 LDS broadcast; affine parts and log2(e) folded into
// pre-scaled weights:
//   z'_i = xin'[t][i] + sum_j (-4*kS*W_hh[i][j]) r_j
//   xin'[t][i] = 2*kS*(b_ih+b_hh+rowsum_i + W_ih[i]·x_t)
// Step tail: t = exp2(z'); r = rcp(1+t).  h_sum = Tp - 2*sum(r).
// This structure measured 567 us (best dispatches ~520 us = ~520 cyc/step
// at ~2.0 GHz sustained): write->read LDS turnaround (~240cyc) + read
// pipeline + dots + exp2/rcp tail. Rounds 5/6/7 probed fence removal,
// staged waits, and 2-chain interleave -- all null or worse; this is the
// structural floor of the LDS-broadcast recurrence.
__global__ __launch_bounds__(128) void rnn_fused(
    const float* __restrict__ x,
    const float* __restrict__ W_ih,
    const float* __restrict__ W_hh,
    const float* __restrict__ b_ih,
    const float* __restrict__ b_hh,
    const float* __restrict__ W_fc,
    const float* __restrict__ b_fc,
    float* __restrict__ out)
{
  const int b = blockIdx.x;
  const int lane = threadIdx.x & 63;   // hidden unit index
  const int wave = threadIdx.x >> 6;

  __shared__ __align__(16) float    xinbuf[2][kCT][kH];  // 32 KB double buffer
  __shared__ __align__(16) _Float16 rbuf[kH];            // r broadcast (fp16)
  __shared__ __align__(16) float    aggbuf[kH];          // epilogue

  // Both waves need bias' = 2*kS*(b_ih + b_hh + rowsum(W_hh row lane)).
  float rowsum = 0.0f;
#pragma unroll
  for (int j = 0; j < kH; j += 4) {
    float4 v = *(const float4*)(W_hh + lane * kH + j);
    rowsum += (v.x + v.y) + (v.z + v.w);
  }
  const float bias2 = 2.0f * kS * (b_ih[lane] + b_hh[lane] + rowsum);

  if (wave == 1) {
    // ================= producer =================
    asm volatile("s_setprio 0");  // never contend with the serial chain
    v2f wi2[kI / 2];  // 2*kS*W_ih[lane][i]
#pragma unroll
    for (int i = 0; i < kI; i += 4) {
      float4 v = *(const float4*)(W_ih + lane * kI + i);
      wi2[i / 2 + 0] = v2f{2.0f * kS * v.x, 2.0f * kS * v.y};
      wi2[i / 2 + 1] = v2f{2.0f * kS * v.z, 2.0f * kS * v.w};
    }
    const float* xb = x + (size_t)b * kT * kI;

    auto fill = [&](int c, int buf) {
      const float* src = xb + (size_t)c * kCT * kI;
#pragma unroll 2
      for (int t = 0; t < kCT; ++t) {
        const float4* row = (const float4*)(src + t * kI);  // broadcast loads
        v2f a0 = v2f{0.0f, 0.0f}, a1 = v2f{0.0f, 0.0f};
#pragma unroll
        for (int i2 = 0; i2 < 8; ++i2) {
          float4 v = row[i2];
          pk_fma(a0, wi2[2 * i2 + 0], v2f{v.x, v.y});
          pk_fma(a1, wi2[2 * i2 + 1], v2f{v.z, v.w});
        }
        xinbuf[buf][t][lane] = bias2 + ((a0.x + a0.y) + (a1.x + a1.y));
      }
    };

    fill(0, 0);
    __syncthreads();  // buffer 0 ready
    for (int c = 0; c < kNC; ++c) {
      if (c + 1 < kNC) fill(c + 1, (c + 1) & 1);
      __syncthreads();  // end of chunk c: consumer done with buf c&1
    }
    return;
  }

  // ================= consumer (wave 0) =================
  asm volatile("s_setprio 3");  // the serial chain wins issue arbitration
  v2h wh[kH / 2];  // -4*kS*W_hh[lane][j] as fp16 pairs
#pragma unroll
  for (int j = 0; j < kH; j += 2) {
    float w0 = W_hh[lane * kH + j + 0];
    float w1 = W_hh[lane * kH + j + 1];
    wh[j / 2] = v2h{(_Float16)(-4.0f * kS * w0), (_Float16)(-4.0f * kS * w1)};
  }

  float r = 0.5f;     // represents h0 = 0
  float rsum = 0.0f;

  const uint4* rb4 = (const uint4*)rbuf;

  // One recurrence step. xin_p==nullptr (compile-time) => pad step.
  auto step = [&](const float* xin_p) {
    float za = xin_p ? *xin_p : bias2;  // ds_read_b32, independent of rbuf
    rbuf[lane] = (_Float16)r;           // ds_write_b16 — head of the chain
    // In-order DS: these reads observe the write above; compiler inserts
    // fine-grained lgkm waits between read returns and dependent dots.
    uint4 q0 = rb4[0], q1 = rb4[1], q2 = rb4[2], q3 = rb4[3];
    uint4 q4 = rb4[4], q5 = rb4[5], q6 = rb4[6], q7 = rb4[7];
    float zb = 0.0f, zc = 0.0f, zd = 0.0f;
    za = dot2(as_h2(q0.x), wh[0], za);
    zb = dot2(as_h2(q0.y), wh[1], zb);
    zc = dot2(as_h2(q0.z), wh[2], zc);
    zd = dot2(as_h2(q0.w), wh[3], zd);
    za = dot2(as_h2(q1.x), wh[4], za);
    zb = dot2(as_h2(q1.y), wh[5], zb);
    zc = dot2(as_h2(q1.z), wh[6], zc);
    zd = dot2(as_h2(q1.w), wh[7], zd);
    za = dot2(as_h2(q2.x), wh[8], za);
    zb = dot2(as_h2(q2.y), wh[9], zb);
    zc = dot2(as_h2(q2.z), wh[10], zc);
    zd = dot2(as_h2(q2.w), wh[11], zd);
    za = dot2(as_h2(q3.x), wh[12], za);
    zb = dot2(as_h2(q3.y), wh[13], zb);
    zc = dot2(as_h2(q3.z), wh[14], zc);
    zd = dot2(as_h2(q3.w), wh[15], zd);
    za = dot2(as_h2(q4.x), wh[16], za);
    zb = dot2(as_h2(q4.y), wh[17], zb);
    zc = dot2(as_h2(q4.z), wh[18], zc);
    zd = dot2(as_h2(q4.w), wh[19], zd);
    za = dot2(as_h2(q5.x), wh[20], za);
    zb = dot2(as_h2(q5.y), wh[21], zb);
    zc = dot2(as_h2(q5.z), wh[22], zc);
    zd = dot2(as_h2(q5.w), wh[23], zd);
    za = dot2(as_h2(q6.x), wh[24], za);
    zb = dot2(as_h2(q6.y), wh[25], zb);
    zc = dot2(as_h2(q6.z), wh[26], zc);
    zd = dot2(as_h2(q6.w), wh[27], zd);
    za = dot2(as_h2(q7.x), wh[28], za);
    zb = dot2(as_h2(q7.y), wh[29], zb);
    zc = dot2(as_h2(q7.z), wh[30], zc);
    zd = dot2(as_h2(q7.w), wh[31], zd);
    float z2 = (za + zb) + (zc + zd);   // = 2*z*log2e
    float t = exp2_fast(z2);            // 2^{z'} = e^{2z}; inf -> r = 0
    r = __builtin_amdgcn_rcpf(1.0f + t);
    rsum += r;
  };

  // left padding: 2 steps with x = 0 (overlaps producer's first fill)
  step(nullptr);
  step(nullptr);
  __syncthreads();  // buffer 0 ready

  for (int c = 0; c < kNC; ++c) {
    const float* xp = &xinbuf[c & 1][0][lane];
#pragma unroll 4
    for (int t = 0; t < kCT; ++t) {
      step(xp);
      xp += kH;
    }
    __syncthreads();  // done with buf c&1
  }

  // right padding: 3 steps with x = 0
  step(nullptr);
  step(nullptr);
  step(nullptr);

  // ---- epilogue: mean over Tp, FC (16x64) + ReLU (single wave: in-order) ----
  aggbuf[lane] = 1.0f - 2.0f * rsum * (1.0f / (float)kTp);
  if (lane < kO) {
    float acc = b_fc[lane];
    const float* wf = W_fc + lane * kH;
#pragma unroll
    for (int j = 0; j < kH; ++j)
      acc = fmaf(wf[j], aggbuf[j], acc);
    out[b * kO + lane] = fmaxf(acc, 0.0f);
  }
}

extern "C" void kernel_launch(void* const* d_in, const int* in_sizes, int n_in,
                              void* d_out, int out_size, void* d_ws, size_t ws_size,
                              hipStream_t stream) {
  const float* x    = (const float*)d_in[0];
  const float* W_ih = (const float*)d_in[1];
  const float* W_hh = (const float*)d_in[2];
  const float* b_ih = (const float*)d_in[3];
  const float* b_hh = (const float*)d_in[4];
  const float* W_fc = (const float*)d_in[5];
  const float* b_fc = (const float*)d_in[6];
  float* out = (float*)d_out;

  rnn_fused<<<dim3(kB), dim3(128), 0, stream>>>(x, W_ih, W_hh, b_ih, b_hh,
                                                W_fc, b_fc, out);
}